// Round 11
// baseline (221.311 us; speedup 1.0000x reference)
//
#include <hip/hip_runtime.h>

#define CH 128
#define CHUNK 4096
#define SLOTS 32768   // per-bucket capacity in gapped cpk/rpk (avg fill ~6250)
#define SCAP 8192     // LDS staging capacity in kb_csrg1 (32KB; mean 6250, sigma~79)

typedef float v2f __attribute__((ext_vector_type(2)));
typedef __attribute__((ext_vector_type(8))) short bf16x8;   // 8 bf16 (4 VGPRs)
typedef __attribute__((ext_vector_type(4))) float f32x4;    // MFMA acc

// ---------------------------------------------------------------- fp8 helpers (OCP e4m3)
// Packed accumulation: v2f += v2f emits v_pk_add_f32.

__device__ __forceinline__ void fp8acc4(unsigned w, v2f* a) {
  a[0] += __builtin_amdgcn_cvt_pk_f32_fp8(w, false);
  a[1] += __builtin_amdgcn_cvt_pk_f32_fp8(w, true);
}
__device__ __forceinline__ void fp8acc16(uint4 v, v2f* a) {
  fp8acc4(v.x, a); fp8acc4(v.y, a + 2); fp8acc4(v.z, a + 4); fp8acc4(v.w, a + 6);
}
__device__ __forceinline__ unsigned fp8pk4(float a, float b, float c, float d) {
  int w = 0;
  w = __builtin_amdgcn_cvt_pk_fp8_f32(a, b, w, false);
  w = __builtin_amdgcn_cvt_pk_fp8_f32(c, d, w, true);
  return (unsigned)w;
}

// ---------------------------------------------------------------- bf16 helpers

__device__ __forceinline__ unsigned bfpack2(float a, float b) {
  unsigned ua = __float_as_uint(a); ua += 0x7FFF + ((ua >> 16) & 1);
  unsigned ub = __float_as_uint(b); ub += 0x7FFF + ((ub >> 16) & 1);
  return (ua >> 16) | (ub & 0xFFFF0000u);
}
__device__ __forceinline__ ushort bf16of(float a) {
  unsigned ua = __float_as_uint(a); ua += 0x7FFF + ((ua >> 16) & 1);
  return (ushort)(ua >> 16);
}

// ---------------------------------------------------------------- utilities

__device__ __forceinline__ int edge_at(const void* ei, long long i, int is64) {
  if (is64) return (int)((const long long*)ei)[i];
  return ((const int*)ei)[i];
}

__device__ __forceinline__ int detect64(const void* ei) {
  int lane = threadIdx.x & 63;
  int v = ((const int*)ei)[2 * lane + 1];
  return (__ballot(v != 0) == 0ULL) ? 1 : 0;
}

// shared gather-accumulate over one node's in-edges (16-deep MLP unroll)
__device__ __forceinline__ void gather_row(const uint4* __restrict__ hb,
                                           const int* __restrict__ rowptr,
                                           const int* __restrict__ src,
                                           int c, int tx, v2f* acc) {
  fp8acc16(hb[(size_t)c * 8 + tx], acc);  // self-loop
  int j = rowptr[c], je = rowptr[c + 1];
  for (; j < je && (j & 3); ++j) fp8acc16(hb[(size_t)src[j] * 8 + tx], acc);
  for (; j + 16 <= je; j += 16) {
    int4 s0 = *(const int4*)(src + j);
    int4 s1 = *(const int4*)(src + j + 4);
    int4 s2 = *(const int4*)(src + j + 8);
    int4 s3 = *(const int4*)(src + j + 12);
    uint4 v0 = hb[(size_t)s0.x * 8 + tx];
    uint4 v1 = hb[(size_t)s0.y * 8 + tx];
    uint4 v2 = hb[(size_t)s0.z * 8 + tx];
    uint4 v3 = hb[(size_t)s0.w * 8 + tx];
    uint4 v4 = hb[(size_t)s1.x * 8 + tx];
    uint4 v5 = hb[(size_t)s1.y * 8 + tx];
    uint4 v6 = hb[(size_t)s1.z * 8 + tx];
    uint4 v7 = hb[(size_t)s1.w * 8 + tx];
    uint4 v8 = hb[(size_t)s2.x * 8 + tx];
    uint4 v9 = hb[(size_t)s2.y * 8 + tx];
    uint4 va = hb[(size_t)s2.z * 8 + tx];
    uint4 vb = hb[(size_t)s2.w * 8 + tx];
    uint4 vc = hb[(size_t)s3.x * 8 + tx];
    uint4 vd = hb[(size_t)s3.y * 8 + tx];
    uint4 ve = hb[(size_t)s3.z * 8 + tx];
    uint4 vf = hb[(size_t)s3.w * 8 + tx];
    fp8acc16(v0, acc); fp8acc16(v1, acc); fp8acc16(v2, acc); fp8acc16(v3, acc);
    fp8acc16(v4, acc); fp8acc16(v5, acc); fp8acc16(v6, acc); fp8acc16(v7, acc);
    fp8acc16(v8, acc); fp8acc16(v9, acc); fp8acc16(va, acc); fp8acc16(vb, acc);
    fp8acc16(vc, acc); fp8acc16(vd, acc); fp8acc16(ve, acc); fp8acc16(vf, acc);
  }
  if (j + 8 <= je) {
    int4 s0 = *(const int4*)(src + j);
    int4 s1 = *(const int4*)(src + j + 4);
    uint4 v0 = hb[(size_t)s0.x * 8 + tx];
    uint4 v1 = hb[(size_t)s0.y * 8 + tx];
    uint4 v2 = hb[(size_t)s0.z * 8 + tx];
    uint4 v3 = hb[(size_t)s0.w * 8 + tx];
    uint4 v4 = hb[(size_t)s1.x * 8 + tx];
    uint4 v5 = hb[(size_t)s1.y * 8 + tx];
    uint4 v6 = hb[(size_t)s1.z * 8 + tx];
    uint4 v7 = hb[(size_t)s1.w * 8 + tx];
    fp8acc16(v0, acc); fp8acc16(v1, acc); fp8acc16(v2, acc); fp8acc16(v3, acc);
    fp8acc16(v4, acc); fp8acc16(v5, acc); fp8acc16(v6, acc); fp8acc16(v7, acc);
    j += 8;
  }
  if (j + 4 <= je) {
    int4 s0 = *(const int4*)(src + j);
    uint4 v0 = hb[(size_t)s0.x * 8 + tx];
    uint4 v1 = hb[(size_t)s0.y * 8 + tx];
    uint4 v2 = hb[(size_t)s0.z * 8 + tx];
    uint4 v3 = hb[(size_t)s0.w * 8 + tx];
    fp8acc16(v0, acc); fp8acc16(v1, acc); fp8acc16(v2, acc); fp8acc16(v3, acc);
    j += 4;
  }
  for (; j < je; ++j) fp8acc16(hb[(size_t)src[j] * 8 + tx], acc);
}

// P1: SINGLE-PASS dual bucket-scatter into GAPPED runs. Blocks >= nCk do
// weight prep. cpk = r|((c&255)<<24), rpk mirrored.
__global__ __launch_bounds__(256) void kb_scat(const void* ei,
                                               int* gcur, int* rcur,
                                               unsigned* __restrict__ cpk,
                                               unsigned* __restrict__ rpk,
                                               const float* __restrict__ W1,
                                               const float* __restrict__ b1,
                                               const float* __restrict__ W2,
                                               const float* __restrict__ b2,
                                               ushort* __restrict__ Wt1,
                                               ushort* __restrict__ Wt2,
                                               float* __restrict__ b1p,
                                               float* __restrict__ b2p,
                                               int E, int N, int nCk) {
  int t = threadIdx.x;
  if ((int)blockIdx.x >= nCk) {  // ---- weight-prep blocks
    int pb = blockIdx.x - nCk;   // 0..15
    int base = pb * 1024;
#pragma unroll
    for (int k = 0; k < 4; ++k) {
      int i = base + k * 256 + t;
      int n = i >> 7, kk = i & 127;
      Wt1[i] = bf16of(W1[(size_t)kk * CH + n]);
      int ko = (kk & 7) * 16 + (kk >> 3);
      Wt2[i] = bf16of(W2[(size_t)ko * CH + n]);
    }
    if (pb == 0 && t < CH) b1p[t] = b1[(t & 7) * 16 + (t >> 3)];
    if (pb == 1 && t < CH) b2p[t] = b2[(t & 7) * 16 + (t >> 3)];
    return;
  }
  __shared__ int hist[256], lcur[256], gbl[256];
  int e0 = blockIdx.x * CHUNK;
  int f = detect64(ei);
  int rr[16], cc[16];
#pragma unroll
  for (int k = 0; k < 16; ++k) {
    int e = e0 + k * 256 + t;
    rr[k] = 0; cc[k] = -1;
    if (e < E) {
      int r = edge_at(ei, e, f);
      int c = edge_at(ei, (long long)E + e, f);
      if ((unsigned)r < (unsigned)N && (unsigned)c < (unsigned)N) { rr[k] = r; cc[k] = c; }
    }
  }
  // ---- pass 1: key = c
  hist[t] = 0;
  __syncthreads();
#pragma unroll
  for (int k = 0; k < 16; ++k)
    if (cc[k] >= 0) atomicAdd(&hist[cc[k] >> 8], 1);
  __syncthreads();
  if (hist[t] > 0) gbl[t] = atomicAdd(&gcur[t * 16], hist[t]);
  lcur[t] = 0;
  __syncthreads();
#pragma unroll
  for (int k = 0; k < 16; ++k) {
    if (cc[k] >= 0) {
      int b = cc[k] >> 8;
      int pos = gbl[b] + atomicAdd(&lcur[b], 1);
      if (pos < SLOTS)
        cpk[(size_t)b * SLOTS + pos] = (unsigned)rr[k] | ((unsigned)(cc[k] & 255) << 24);
    }
  }
  __syncthreads();
  // ---- pass 2: key = r
  hist[t] = 0;
  __syncthreads();
#pragma unroll
  for (int k = 0; k < 16; ++k)
    if (cc[k] >= 0) atomicAdd(&hist[rr[k] >> 8], 1);
  __syncthreads();
  if (hist[t] > 0) gbl[t] = atomicAdd(&rcur[t * 16], hist[t]);
  lcur[t] = 0;
  __syncthreads();
#pragma unroll
  for (int k = 0; k < 16; ++k) {
    if (cc[k] >= 0) {
      int b = rr[k] >> 8;
      int pos = gbl[b] + atomicAdd(&lcur[b], 1);
      if (pos < SLOTS)
        rpk[(size_t)b * SLOTS + pos] = (unsigned)cc[k] | ((unsigned)(rr[k] & 255) << 24);
    }
  }
}

// P2 (fused): per-bucket CSR build + dinv + LDS-staged src write-out, THEN
// the layer-1 MFMA GEMM with register-prefetched inputs.
__global__ __launch_bounds__(1024) void kb_csrg1(const unsigned* __restrict__ cpk,
                                                 const int* __restrict__ gcur,
                                                 int* rowptr, int* src,
                                                 float* __restrict__ dinv,
                                                 const float* __restrict__ Ain,
                                                 const ushort* __restrict__ Wt,
                                                 uint2* __restrict__ Cb, int N) {
  __shared__ int hist[256], lcur[256], tmp[256];
  __shared__ float dloc[256];
  __shared__ int baseSh;
  __shared__ int srcl[SCAP];                         // 32KB staging
  __shared__ __align__(16) ushort As[256 * 136];     // 69.6KB
  __shared__ __align__(16) ushort Bs[128 * 136];     // 34.8KB
  int t = threadIdx.x;
  int b = blockIdx.x;
  int node0 = b << 8;
  int nn = min(256, N - node0);
  int cnt = min(gcur[b * 16], SLOTS);

  // ---- prefetch GEMM inputs into registers (loads fly during CSR phases)
  float4 xa[8];
  {
    const float4* A = (const float4*)Ain;  // [N][32]
    int k4 = t & 31, m0 = t >> 5;          // m0 in 0..31
#pragma unroll
    for (int i = 0; i < 8; ++i) {
      int gr = node0 + m0 + i * 32;
      xa[i] = (gr < N) ? A[(size_t)gr * 32 + k4] : make_float4(0.f, 0.f, 0.f, 0.f);
    }
  }
  uint4 wb0, wb1;
  {
    const uint4* W4 = (const uint4*)Wt;
    int rw = t >> 3, q = t & 7;            // rw in 0..127
    wb0 = W4[rw * 16 + 2 * q];
    wb1 = W4[rw * 16 + 2 * q + 1];
  }
  // ---- prefetch cpk run (single read; 8-deep covers cnt<=8192)
  const unsigned* reg = cpk + (size_t)b * SLOTS;
  unsigned wc[8];
#pragma unroll
  for (int i = 0; i < 8; ++i) {
    int j = t + i * 1024;
    wc[i] = (j < cnt) ? reg[j] : 0xFFFFFFFFu;
  }

  // local exclusive scan of (clamped) bucket counts -> compact base
  if (t < 256) tmp[t] = min(gcur[t * 16], SLOTS);
  __syncthreads();
  for (int off = 1; off < 256; off <<= 1) {
    int u = (t < 256 && t >= off) ? tmp[t - off] : 0;
    __syncthreads();
    if (t < 256) tmp[t] += u;
    __syncthreads();
  }
  if (t == 0) baseSh = tmp[b] - cnt;
  __syncthreads();
  int base = baseSh;
  if (b == (int)gridDim.x - 1 && t == 0) rowptr[N] = base + cnt;

  if (t < 256) hist[t] = 0;
  __syncthreads();
#pragma unroll
  for (int i = 0; i < 8; ++i)
    if (wc[i] != 0xFFFFFFFFu) atomicAdd(&hist[wc[i] >> 24], 1);
  for (int j = t + 8192; j < cnt; j += 1024)
    atomicAdd(&hist[reg[j] >> 24], 1);
  __syncthreads();
  if (t < 256) tmp[t] = hist[t];
  __syncthreads();
  for (int off = 1; off < 256; off <<= 1) {
    int u = (t < 256 && t >= off) ? tmp[t - off] : 0;
    __syncthreads();
    if (t < 256) tmp[t] += u;
    __syncthreads();
  }
  if (t < 256) {
    int v = hist[t];
    lcur[t] = tmp[t] - v;
    float dv = rsqrtf((float)(v + 1));  // +1 self-loop
    dloc[t] = dv;
    if (t < nn) {
      rowptr[node0 + t] = base + tmp[t] - v;
      dinv[node0 + t] = dv;
    }
  }
  __syncthreads();
#pragma unroll
  for (int i = 0; i < 8; ++i) {
    unsigned w = wc[i];
    if (w != 0xFFFFFFFFu) {
      int pos = atomicAdd(&lcur[w >> 24], 1);
      if (pos < SCAP) srcl[pos] = (int)(w & 0xFFFFFF);
      else            src[base + pos] = (int)(w & 0xFFFFFF);  // overflow fallback
    }
  }
  for (int j = t + 8192; j < cnt; j += 1024) {
    unsigned w = reg[j];
    int pos = atomicAdd(&lcur[w >> 24], 1);
    if (pos < SCAP) srcl[pos] = (int)(w & 0xFFFFFF);
    else            src[base + pos] = (int)(w & 0xFFFFFF);
  }
  __syncthreads();
  int mo = min(cnt, SCAP);
  for (int j = t; j < mo; j += 1024) src[base + j] = srcl[j];

  // ---- phase B: layer-1 GEMM for rows [node0, node0+256) — from registers
  {
    int k4 = t & 31, m0 = t >> 5;
#pragma unroll
    for (int i = 0; i < 8; ++i) {
      int mm = m0 + i * 32;
      *(uint2*)&As[mm * 136 + k4 * 4] =
          make_uint2(bfpack2(xa[i].x, xa[i].y), bfpack2(xa[i].z, xa[i].w));
    }
    int rw = t >> 3, q = t & 7;
    *(uint4*)&Bs[rw * 136 + q * 16] = wb0;
    *(uint4*)&Bs[rw * 136 + q * 16 + 8] = wb1;
  }
  __syncthreads();

  int lane = t & 63, w = t >> 6;  // w in 0..15 -> 16 row-tiles of 16
  int m = lane & 15, quad = lane >> 4;
  f32x4 acc[8] = {};
#pragma unroll
  for (int kb = 0; kb < 128; kb += 32) {
    bf16x8 af = *(const bf16x8*)&As[(w * 16 + m) * 136 + kb + quad * 8];
#pragma unroll
    for (int nt = 0; nt < 8; ++nt) {
      bf16x8 bfv = *(const bf16x8*)&Bs[(nt * 16 + m) * 136 + kb + quad * 8];
      acc[nt] = __builtin_amdgcn_mfma_f32_16x16x32_bf16(af, bfv, acc[nt], 0, 0, 0);
    }
  }
#pragma unroll
  for (int rg = 0; rg < 4; ++rg) {
    int lr = w * 16 + quad * 4 + rg;
    int gr = node0 + lr;
    if (gr < N) {
      float s = dloc[lr];
      unsigned w0 = fp8pk4(acc[0][rg] * s, acc[1][rg] * s, acc[2][rg] * s, acc[3][rg] * s);
      unsigned w1 = fp8pk4(acc[4][rg] * s, acc[5][rg] * s, acc[6][rg] * s, acc[7][rg] * s);
      Cb[(size_t)gr * 16 + m] = make_uint2(w0, w1);
    }
  }
}

// ---------------------------------------------------------------- fused agg1 + GEMM2 (+wp)
// Blocks >= gblocks compute wp from gapped r-runs — hidden under the gather.
__global__ __launch_bounds__(256) void k_aggemm(const uint4* __restrict__ hb,
                                                const float* __restrict__ dinv,
                                                const int* __restrict__ rowptr,
                                                const int* __restrict__ src,
                                                const float* __restrict__ biasH,
                                                const ushort* __restrict__ Wt,
                                                uint2* __restrict__ Cb,
                                                const unsigned* __restrict__ rpk,
                                                const int* __restrict__ rcur,
                                                float* __restrict__ wp,
                                                int N, int gblocks) {
  __shared__ __align__(16) ushort As[64 * 136];
  __shared__ __align__(16) ushort Bs[128 * 136];
  int t = threadIdx.x;

  if ((int)blockIdx.x >= gblocks) {  // ---- wp side-blocks
    float* wpl = (float*)As;  // 256 floats
    int b = blockIdx.x - gblocks;
    int node0 = b << 8;
    int nn = min(256, N - node0);
    int cnt = min(rcur[b * 16], SLOTS);
    wpl[t] = 0.f;
    __syncthreads();
    const unsigned* reg = rpk + (size_t)b * SLOTS;
    for (int j = t; j < cnt; j += 256) {
      unsigned w = reg[j];
      atomicAdd(&wpl[w >> 24], dinv[w & 0xFFFFFF]);
    }
    __syncthreads();
    if (t < nn) wp[node0 + t] = wpl[t];
    return;
  }

  int row0 = blockIdx.x * 64;
  {  // stage W2 while agg runs
    const uint4* W4 = (const uint4*)Wt;
    int rw = t >> 1, half = t & 1;
#pragma unroll
    for (int i = 0; i < 8; ++i) {
      uint4 v = W4[rw * 16 + half * 8 + i];
      *(uint4*)&Bs[rw * 136 + half * 64 + i * 8] = v;
    }
  }

  int tx = t & 7, ty = t >> 3;  // (8,32)
  float bv[16];
#pragma unroll
  for (int i = 0; i < 16; ++i) bv[i] = biasH[tx * 16 + i];

#pragma unroll
  for (int half = 0; half < 2; ++half) {
    int row = half * 32 + ty;
    int c = row0 + row;
    float o[16];
    if (c < N) {
      v2f acc[8] = {};
      gather_row(hb, rowptr, src, c, tx, acc);
      float s = dinv[c];
#pragma unroll
      for (int i = 0; i < 16; ++i) o[i] = fmaxf(acc[i >> 1][i & 1] * s + bv[i], 0.f);
    } else {
#pragma unroll
      for (int i = 0; i < 16; ++i) o[i] = 0.f;
    }
#pragma unroll
    for (int i = 0; i < 8; ++i)
      *(unsigned*)&As[row * 136 + tx * 16 + 2 * i] = bfpack2(o[2 * i], o[2 * i + 1]);
  }
  __syncthreads();

  int lane = t & 63, w = t >> 6;
  int m = lane & 15, quad = lane >> 4;
  f32x4 acc[8] = {};
#pragma unroll
  for (int kb = 0; kb < 128; kb += 32) {
    bf16x8 af = *(const bf16x8*)&As[(w * 16 + m) * 136 + kb + quad * 8];
#pragma unroll
    for (int nt = 0; nt < 8; ++nt) {
      bf16x8 bfv = *(const bf16x8*)&Bs[(nt * 16 + m) * 136 + kb + quad * 8];
      acc[nt] = __builtin_amdgcn_mfma_f32_16x16x32_bf16(af, bfv, acc[nt], 0, 0, 0);
    }
  }
#pragma unroll
  for (int reg = 0; reg < 4; ++reg) {
    int gr = row0 + w * 16 + quad * 4 + reg;
    if (gr < N) {
      float s = dinv[gr];
      unsigned w0 = fp8pk4(acc[0][reg] * s, acc[1][reg] * s, acc[2][reg] * s, acc[3][reg] * s);
      unsigned w1 = fp8pk4(acc[4][reg] * s, acc[5][reg] * s, acc[6][reg] * s, acc[7][reg] * s);
      Cb[(size_t)gr * 16 + m] = make_uint2(w0, w1);
    }
  }
}

// ---------------------------------------------------------------- FINAL aggregate + epilogue
// Layer-2 aggregate with layer-3 collapse. Last-finishing block runs the
// epilogue. Ordering WITHOUT threadfence (r4: per-block device fence collapsed
// gather rate 3x): part atomicAdds use the RETURNING form and the returned
// value is consumed (forces wait for completion at the coherent point) BEFORE
// the ticket atomic. Winner reads part via atomicAdd(p,0) (coherent reads).
__global__ __launch_bounds__(256) void k_aggfin(const uint4* __restrict__ hb,
                                                const float* __restrict__ dinv,
                                                const float* __restrict__ wp,
                                                const int* __restrict__ rowptr,
                                                const int* __restrict__ src,
                                                const float* __restrict__ biasH,
                                                float* __restrict__ part,
                                                int* __restrict__ ticket,
                                                const float* __restrict__ W3,
                                                const float* __restrict__ b3,
                                                const float* __restrict__ Wl,
                                                const float* __restrict__ bl,
                                                float* __restrict__ out,
                                                float invN, int N) {
  int t = threadIdx.x;
  int tx = t & 7, ty = t >> 3;  // (8,32)
  float bv[16];
#pragma unroll
  for (int i = 0; i < 16; ++i) bv[i] = biasH[tx * 16 + i];
  float wacc[16];
#pragma unroll
  for (int i = 0; i < 16; ++i) wacc[i] = 0.f;

  for (int c = blockIdx.x * 32 + ty; c < N; c += gridDim.x * 32) {
    v2f acc[8] = {};
    gather_row(hb, rowptr, src, c, tx, acc);
    float s = dinv[c];
    float wt = (s + wp[c]) * s;
#pragma unroll
    for (int i = 0; i < 16; ++i)
      wacc[i] += wt * fmaxf(acc[i >> 1][i & 1] * s + bv[i], 0.f);
  }

  // wave reduce across ty (lane = ty*8+tx)
#pragma unroll
  for (int i = 0; i < 16; ++i) {
    wacc[i] += __shfl_down(wacc[i], 32);
    wacc[i] += __shfl_down(wacc[i], 16);
    wacc[i] += __shfl_down(wacc[i], 8);
  }
  __shared__ float redw[4][8][16];
  int wv = ty >> 3;
  if ((ty & 7) == 0) {
#pragma unroll
    for (int i = 0; i < 16; ++i) redw[wv][tx][i] = wacc[i];
  }
  __syncthreads();
  float dummy = 0.f;
  if (t < 128) {
    int cx = t >> 4, i = t & 15;
    float sum = redw[0][cx][i] + redw[1][cx][i] + redw[2][cx][i] + redw[3][cx][i];
    dummy = atomicAdd(&part[(size_t)(blockIdx.x & 63) * CH + cx * 16 + i], sum);
  }
  asm volatile("" :: "v"(dummy));  // consume -> wait for atomic completion
  __syncthreads();
  __shared__ int amLast;
  if (t == 0) amLast = (atomicAdd(ticket, 1) == (int)gridDim.x - 1);
  __syncthreads();
  if (!amLast) return;

  // ---- epilogue (256 threads; winner block only)
  __shared__ float us[CH];
  __shared__ float red2[2][CH];
  if (t < CH) {
    float s = 0.f;
    for (int q = 0; q < 64; ++q) s += atomicAdd(&part[(size_t)q * CH + t], 0.f);
    us[t] = s * invN;
  }
  __syncthreads();
  int ch = t & 127, g = t >> 7;
  float p = 0.f;
#pragma unroll
  for (int k = 0; k < 64; ++k) {
    int kk = g * 64 + k;
    int ko = (kk & 7) * 16 + (kk >> 3);  // un-permute channel
    p += us[kk] * W3[(size_t)ko * CH + ch];
  }
  red2[g][ch] = p;
  __syncthreads();
  if (t < CH) us[t] = (red2[0][t] + red2[1][t] + b3[t]) * Wl[t];
  __syncthreads();
  for (int off = 64; off > 0; off >>= 1) {
    if (t < off) us[t] += us[t + off];
    __syncthreads();
  }
  if (t == 0) out[0] = 1.f / (1.f + expf(-(us[0] + bl[0])));
}

// ---------------------------------------------------------------- launch

extern "C" void kernel_launch(void* const* d_in, const int* in_sizes, int n_in,
                              void* d_out, int out_size, void* d_ws, size_t ws_size,
                              hipStream_t stream) {
  const float* x  = (const float*)d_in[0];
  const void*  ei = d_in[1];
  const float* W1 = (const float*)d_in[3];
  const float* b1 = (const float*)d_in[4];
  const float* W2 = (const float*)d_in[5];
  const float* b2 = (const float*)d_in[6];
  const float* W3 = (const float*)d_in[7];
  const float* b3 = (const float*)d_in[8];
  const float* Wl = (const float*)d_in[9];
  const float* bl = (const float*)d_in[10];
  float* out = (float*)d_out;

  const int N = in_sizes[0] / CH;
  const int E = in_sizes[1] / 2;
  const int NB = (N + 255) >> 8;

  char* ws = (char*)d_ws;
  size_t off = 0;
  auto alloc = [&](size_t bytes) -> void* {
    void* p = ws + off;
    off += (bytes + 511) & ~(size_t)511;
    return p;
  };
  float*    dinv   = (float*)alloc((size_t)N * 4);
  int*      rowptr = (int*)alloc((size_t)(N + 1) * 4);
  ushort*   Wt1    = (ushort*)alloc(128 * 128 * 2);
  ushort*   Wt2    = (ushort*)alloc(128 * 128 * 2);
  float*    b1p    = (float*)alloc(CH * 4);
  float*    b2p    = (float*)alloc(CH * 4);
  float*    wp     = (float*)alloc((size_t)N * 4);
  int*      src    = (int*)alloc((size_t)E * 4);
  unsigned* cpk    = (unsigned*)alloc((size_t)256 * SLOTS * 4);  // gapped
  unsigned* rpk    = (unsigned*)alloc((size_t)256 * SLOTS * 4);  // gapped
  uint4*    hb     = (uint4*)alloc((size_t)N * 128);  // fp8 128B rows
  uint4*    xb     = (uint4*)alloc((size_t)N * 128);
  // ---- contiguous zero-init region (single small memset)
  size_t z0 = off;
  int*      gcur   = (int*)alloc(256 * 16 * 4);
  int*      rcur   = (int*)alloc(256 * 16 * 4);
  float*    part   = (float*)alloc((size_t)64 * CH * 4);
  int*      ticket = (int*)alloc(512);
  size_t zbytes = off - z0;

  const int nCk = (E + CHUNK - 1) / CHUNK;
  const int gblocks = (N + 63) / 64;
  const int pgx = (N + 31) / 32;

  // ---- preprocessing (single-pass scatter; no counting pass)
  hipMemsetAsync(ws + z0, 0, zbytes, stream);
  kb_scat<<<nCk + 16, 256, 0, stream>>>(ei, gcur, rcur, cpk, rpk,
                                        W1, b1, W2, b2, Wt1, Wt2, b1p, b2p, E, N, nCk);
  // ---- CSR build + dinv + layer-1 GEMM (fused; register-prefetched inputs)
  kb_csrg1<<<NB, 1024, 0, stream>>>(cpk, gcur, rowptr, src, dinv, x, Wt1, (uint2*)hb, N);

  // ---- layer-1 aggregate + layer-2 GEMM, with wp side-blocks hidden under it
  k_aggemm<<<gblocks + NB, 256, 0, stream>>>(hb, dinv, rowptr, src, b1p, Wt2, (uint2*)xb,
                                             rpk, rcur, wp, N, gblocks);
  // ---- layer-2 aggregate + layer-3 collapse + ticketed epilogue (no k_final node)
  k_aggfin<<<pgx, 256, 0, stream>>>(xb, dinv, wp, rowptr, src, b2p, part, ticket,
                                    W3, b3, Wl, bl, out, 1.0f / (float)N, N);
}

// Round 12
// 212.285 us; speedup vs baseline: 1.0425x; 1.0425x over previous
//
#include <hip/hip_runtime.h>

#define CH 128
#define CHUNK 4096
#define SLOTS 32768   // per-bucket capacity in gapped cpk/rpk (avg fill ~6250)
#define SCAP 8192     // LDS staging capacity in kb_csrg1 (32KB; mean 6250, sigma~79)

typedef float v2f __attribute__((ext_vector_type(2)));
typedef __attribute__((ext_vector_type(8))) short bf16x8;   // 8 bf16 (4 VGPRs)
typedef __attribute__((ext_vector_type(4))) float f32x4;    // MFMA acc

// ---------------------------------------------------------------- fp8 helpers (OCP e4m3)
// Packed accumulation: v2f += v2f emits v_pk_add_f32.

__device__ __forceinline__ void fp8acc4(unsigned w, v2f* a) {
  a[0] += __builtin_amdgcn_cvt_pk_f32_fp8(w, false);
  a[1] += __builtin_amdgcn_cvt_pk_f32_fp8(w, true);
}
__device__ __forceinline__ void fp8acc16(uint4 v, v2f* a) {
  fp8acc4(v.x, a); fp8acc4(v.y, a + 2); fp8acc4(v.z, a + 4); fp8acc4(v.w, a + 6);
}
__device__ __forceinline__ unsigned fp8pk4(float a, float b, float c, float d) {
  int w = 0;
  w = __builtin_amdgcn_cvt_pk_fp8_f32(a, b, w, false);
  w = __builtin_amdgcn_cvt_pk_fp8_f32(c, d, w, true);
  return (unsigned)w;
}

// ---------------------------------------------------------------- bf16 helpers

__device__ __forceinline__ unsigned bfpack2(float a, float b) {
  unsigned ua = __float_as_uint(a); ua += 0x7FFF + ((ua >> 16) & 1);
  unsigned ub = __float_as_uint(b); ub += 0x7FFF + ((ub >> 16) & 1);
  return (ua >> 16) | (ub & 0xFFFF0000u);
}
__device__ __forceinline__ ushort bf16of(float a) {
  unsigned ua = __float_as_uint(a); ua += 0x7FFF + ((ua >> 16) & 1);
  return (ushort)(ua >> 16);
}

// ---------------------------------------------------------------- utilities

__device__ __forceinline__ int edge_at(const void* ei, long long i, int is64) {
  if (is64) return (int)((const long long*)ei)[i];
  return ((const int*)ei)[i];
}

__device__ __forceinline__ int detect64(const void* ei) {
  int lane = threadIdx.x & 63;
  int v = ((const int*)ei)[2 * lane + 1];
  return (__ballot(v != 0) == 0ULL) ? 1 : 0;
}

// shared gather-accumulate over one node's in-edges (16-deep MLP unroll)
__device__ __forceinline__ void gather_row(const uint4* __restrict__ hb,
                                           const int* __restrict__ rowptr,
                                           const int* __restrict__ src,
                                           int c, int tx, v2f* acc) {
  fp8acc16(hb[(size_t)c * 8 + tx], acc);  // self-loop
  int j = rowptr[c], je = rowptr[c + 1];
  for (; j < je && (j & 3); ++j) fp8acc16(hb[(size_t)src[j] * 8 + tx], acc);
  for (; j + 16 <= je; j += 16) {
    int4 s0 = *(const int4*)(src + j);
    int4 s1 = *(const int4*)(src + j + 4);
    int4 s2 = *(const int4*)(src + j + 8);
    int4 s3 = *(const int4*)(src + j + 12);
    uint4 v0 = hb[(size_t)s0.x * 8 + tx];
    uint4 v1 = hb[(size_t)s0.y * 8 + tx];
    uint4 v2 = hb[(size_t)s0.z * 8 + tx];
    uint4 v3 = hb[(size_t)s0.w * 8 + tx];
    uint4 v4 = hb[(size_t)s1.x * 8 + tx];
    uint4 v5 = hb[(size_t)s1.y * 8 + tx];
    uint4 v6 = hb[(size_t)s1.z * 8 + tx];
    uint4 v7 = hb[(size_t)s1.w * 8 + tx];
    uint4 v8 = hb[(size_t)s2.x * 8 + tx];
    uint4 v9 = hb[(size_t)s2.y * 8 + tx];
    uint4 va = hb[(size_t)s2.z * 8 + tx];
    uint4 vb = hb[(size_t)s2.w * 8 + tx];
    uint4 vc = hb[(size_t)s3.x * 8 + tx];
    uint4 vd = hb[(size_t)s3.y * 8 + tx];
    uint4 ve = hb[(size_t)s3.z * 8 + tx];
    uint4 vf = hb[(size_t)s3.w * 8 + tx];
    fp8acc16(v0, acc); fp8acc16(v1, acc); fp8acc16(v2, acc); fp8acc16(v3, acc);
    fp8acc16(v4, acc); fp8acc16(v5, acc); fp8acc16(v6, acc); fp8acc16(v7, acc);
    fp8acc16(v8, acc); fp8acc16(v9, acc); fp8acc16(va, acc); fp8acc16(vb, acc);
    fp8acc16(vc, acc); fp8acc16(vd, acc); fp8acc16(ve, acc); fp8acc16(vf, acc);
  }
  if (j + 8 <= je) {
    int4 s0 = *(const int4*)(src + j);
    int4 s1 = *(const int4*)(src + j + 4);
    uint4 v0 = hb[(size_t)s0.x * 8 + tx];
    uint4 v1 = hb[(size_t)s0.y * 8 + tx];
    uint4 v2 = hb[(size_t)s0.z * 8 + tx];
    uint4 v3 = hb[(size_t)s0.w * 8 + tx];
    uint4 v4 = hb[(size_t)s1.x * 8 + tx];
    uint4 v5 = hb[(size_t)s1.y * 8 + tx];
    uint4 v6 = hb[(size_t)s1.z * 8 + tx];
    uint4 v7 = hb[(size_t)s1.w * 8 + tx];
    fp8acc16(v0, acc); fp8acc16(v1, acc); fp8acc16(v2, acc); fp8acc16(v3, acc);
    fp8acc16(v4, acc); fp8acc16(v5, acc); fp8acc16(v6, acc); fp8acc16(v7, acc);
    j += 8;
  }
  if (j + 4 <= je) {
    int4 s0 = *(const int4*)(src + j);
    uint4 v0 = hb[(size_t)s0.x * 8 + tx];
    uint4 v1 = hb[(size_t)s0.y * 8 + tx];
    uint4 v2 = hb[(size_t)s0.z * 8 + tx];
    uint4 v3 = hb[(size_t)s0.w * 8 + tx];
    fp8acc16(v0, acc); fp8acc16(v1, acc); fp8acc16(v2, acc); fp8acc16(v3, acc);
    j += 4;
  }
  for (; j < je; ++j) fp8acc16(hb[(size_t)src[j] * 8 + tx], acc);
}

// P1: SINGLE-PASS dual bucket-scatter into GAPPED runs. Blocks >= nCk do
// weight prep. cpk = r|((c&255)<<24), rpk mirrored.
__global__ __launch_bounds__(256) void kb_scat(const void* ei,
                                               int* gcur, int* rcur,
                                               unsigned* __restrict__ cpk,
                                               unsigned* __restrict__ rpk,
                                               const float* __restrict__ W1,
                                               const float* __restrict__ b1,
                                               const float* __restrict__ W2,
                                               const float* __restrict__ b2,
                                               ushort* __restrict__ Wt1,
                                               ushort* __restrict__ Wt2,
                                               float* __restrict__ b1p,
                                               float* __restrict__ b2p,
                                               int E, int N, int nCk) {
  int t = threadIdx.x;
  if ((int)blockIdx.x >= nCk) {  // ---- weight-prep blocks
    int pb = blockIdx.x - nCk;   // 0..15
    int base = pb * 1024;
#pragma unroll
    for (int k = 0; k < 4; ++k) {
      int i = base + k * 256 + t;
      int n = i >> 7, kk = i & 127;
      Wt1[i] = bf16of(W1[(size_t)kk * CH + n]);
      int ko = (kk & 7) * 16 + (kk >> 3);
      Wt2[i] = bf16of(W2[(size_t)ko * CH + n]);
    }
    if (pb == 0 && t < CH) b1p[t] = b1[(t & 7) * 16 + (t >> 3)];
    if (pb == 1 && t < CH) b2p[t] = b2[(t & 7) * 16 + (t >> 3)];
    return;
  }
  __shared__ int hist[256], lcur[256], gbl[256];
  int e0 = blockIdx.x * CHUNK;
  int f = detect64(ei);
  int rr[16], cc[16];
#pragma unroll
  for (int k = 0; k < 16; ++k) {
    int e = e0 + k * 256 + t;
    rr[k] = 0; cc[k] = -1;
    if (e < E) {
      int r = edge_at(ei, e, f);
      int c = edge_at(ei, (long long)E + e, f);
      if ((unsigned)r < (unsigned)N && (unsigned)c < (unsigned)N) { rr[k] = r; cc[k] = c; }
    }
  }
  // ---- pass 1: key = c
  hist[t] = 0;
  __syncthreads();
#pragma unroll
  for (int k = 0; k < 16; ++k)
    if (cc[k] >= 0) atomicAdd(&hist[cc[k] >> 8], 1);
  __syncthreads();
  if (hist[t] > 0) gbl[t] = atomicAdd(&gcur[t * 16], hist[t]);
  lcur[t] = 0;
  __syncthreads();
#pragma unroll
  for (int k = 0; k < 16; ++k) {
    if (cc[k] >= 0) {
      int b = cc[k] >> 8;
      int pos = gbl[b] + atomicAdd(&lcur[b], 1);
      if (pos < SLOTS)
        cpk[(size_t)b * SLOTS + pos] = (unsigned)rr[k] | ((unsigned)(cc[k] & 255) << 24);
    }
  }
  __syncthreads();
  // ---- pass 2: key = r
  hist[t] = 0;
  __syncthreads();
#pragma unroll
  for (int k = 0; k < 16; ++k)
    if (cc[k] >= 0) atomicAdd(&hist[rr[k] >> 8], 1);
  __syncthreads();
  if (hist[t] > 0) gbl[t] = atomicAdd(&rcur[t * 16], hist[t]);
  lcur[t] = 0;
  __syncthreads();
#pragma unroll
  for (int k = 0; k < 16; ++k) {
    if (cc[k] >= 0) {
      int b = rr[k] >> 8;
      int pos = gbl[b] + atomicAdd(&lcur[b], 1);
      if (pos < SLOTS)
        rpk[(size_t)b * SLOTS + pos] = (unsigned)cc[k] | ((unsigned)(rr[k] & 255) << 24);
    }
  }
}

// P2 (fused): per-bucket CSR build + dinv + LDS-staged src write-out, THEN
// the layer-1 MFMA GEMM with register-prefetched inputs.
__global__ __launch_bounds__(1024) void kb_csrg1(const unsigned* __restrict__ cpk,
                                                 const int* __restrict__ gcur,
                                                 int* rowptr, int* src,
                                                 float* __restrict__ dinv,
                                                 const float* __restrict__ Ain,
                                                 const ushort* __restrict__ Wt,
                                                 uint2* __restrict__ Cb, int N) {
  __shared__ int hist[256], lcur[256], tmp[256];
  __shared__ float dloc[256];
  __shared__ int baseSh;
  __shared__ int srcl[SCAP];                         // 32KB staging
  __shared__ __align__(16) ushort As[256 * 136];     // 69.6KB
  __shared__ __align__(16) ushort Bs[128 * 136];     // 34.8KB
  int t = threadIdx.x;
  int b = blockIdx.x;
  int node0 = b << 8;
  int nn = min(256, N - node0);
  int cnt = min(gcur[b * 16], SLOTS);

  // ---- prefetch GEMM inputs into registers (loads fly during CSR phases)
  float4 xa[8];
  {
    const float4* A = (const float4*)Ain;  // [N][32]
    int k4 = t & 31, m0 = t >> 5;          // m0 in 0..31
#pragma unroll
    for (int i = 0; i < 8; ++i) {
      int gr = node0 + m0 + i * 32;
      xa[i] = (gr < N) ? A[(size_t)gr * 32 + k4] : make_float4(0.f, 0.f, 0.f, 0.f);
    }
  }
  uint4 wb0, wb1;
  {
    const uint4* W4 = (const uint4*)Wt;
    int rw = t >> 3, q = t & 7;            // rw in 0..127
    wb0 = W4[rw * 16 + 2 * q];
    wb1 = W4[rw * 16 + 2 * q + 1];
  }
  // ---- prefetch cpk run (single read; 8-deep covers cnt<=8192)
  const unsigned* reg = cpk + (size_t)b * SLOTS;
  unsigned wc[8];
#pragma unroll
  for (int i = 0; i < 8; ++i) {
    int j = t + i * 1024;
    wc[i] = (j < cnt) ? reg[j] : 0xFFFFFFFFu;
  }

  // local exclusive scan of (clamped) bucket counts -> compact base
  if (t < 256) tmp[t] = min(gcur[t * 16], SLOTS);
  __syncthreads();
  for (int off = 1; off < 256; off <<= 1) {
    int u = (t < 256 && t >= off) ? tmp[t - off] : 0;
    __syncthreads();
    if (t < 256) tmp[t] += u;
    __syncthreads();
  }
  if (t == 0) baseSh = tmp[b] - cnt;
  __syncthreads();
  int base = baseSh;
  if (b == (int)gridDim.x - 1 && t == 0) rowptr[N] = base + cnt;

  if (t < 256) hist[t] = 0;
  __syncthreads();
#pragma unroll
  for (int i = 0; i < 8; ++i)
    if (wc[i] != 0xFFFFFFFFu) atomicAdd(&hist[wc[i] >> 24], 1);
  for (int j = t + 8192; j < cnt; j += 1024)
    atomicAdd(&hist[reg[j] >> 24], 1);
  __syncthreads();
  if (t < 256) tmp[t] = hist[t];
  __syncthreads();
  for (int off = 1; off < 256; off <<= 1) {
    int u = (t < 256 && t >= off) ? tmp[t - off] : 0;
    __syncthreads();
    if (t < 256) tmp[t] += u;
    __syncthreads();
  }
  if (t < 256) {
    int v = hist[t];
    lcur[t] = tmp[t] - v;
    float dv = rsqrtf((float)(v + 1));  // +1 self-loop
    dloc[t] = dv;
    if (t < nn) {
      rowptr[node0 + t] = base + tmp[t] - v;
      dinv[node0 + t] = dv;
    }
  }
  __syncthreads();
#pragma unroll
  for (int i = 0; i < 8; ++i) {
    unsigned w = wc[i];
    if (w != 0xFFFFFFFFu) {
      int pos = atomicAdd(&lcur[w >> 24], 1);
      if (pos < SCAP) srcl[pos] = (int)(w & 0xFFFFFF);
      else            src[base + pos] = (int)(w & 0xFFFFFF);  // overflow fallback
    }
  }
  for (int j = t + 8192; j < cnt; j += 1024) {
    unsigned w = reg[j];
    int pos = atomicAdd(&lcur[w >> 24], 1);
    if (pos < SCAP) srcl[pos] = (int)(w & 0xFFFFFF);
    else            src[base + pos] = (int)(w & 0xFFFFFF);
  }
  __syncthreads();
  int mo = min(cnt, SCAP);
  for (int j = t; j < mo; j += 1024) src[base + j] = srcl[j];

  // ---- phase B: layer-1 GEMM for rows [node0, node0+256) — from registers
  {
    int k4 = t & 31, m0 = t >> 5;
#pragma unroll
    for (int i = 0; i < 8; ++i) {
      int mm = m0 + i * 32;
      *(uint2*)&As[mm * 136 + k4 * 4] =
          make_uint2(bfpack2(xa[i].x, xa[i].y), bfpack2(xa[i].z, xa[i].w));
    }
    int rw = t >> 3, q = t & 7;
    *(uint4*)&Bs[rw * 136 + q * 16] = wb0;
    *(uint4*)&Bs[rw * 136 + q * 16 + 8] = wb1;
  }
  __syncthreads();

  int lane = t & 63, w = t >> 6;  // w in 0..15 -> 16 row-tiles of 16
  int m = lane & 15, quad = lane >> 4;
  f32x4 acc[8] = {};
#pragma unroll
  for (int kb = 0; kb < 128; kb += 32) {
    bf16x8 af = *(const bf16x8*)&As[(w * 16 + m) * 136 + kb + quad * 8];
#pragma unroll
    for (int nt = 0; nt < 8; ++nt) {
      bf16x8 bfv = *(const bf16x8*)&Bs[(nt * 16 + m) * 136 + kb + quad * 8];
      acc[nt] = __builtin_amdgcn_mfma_f32_16x16x32_bf16(af, bfv, acc[nt], 0, 0, 0);
    }
  }
#pragma unroll
  for (int rg = 0; rg < 4; ++rg) {
    int lr = w * 16 + quad * 4 + rg;
    int gr = node0 + lr;
    if (gr < N) {
      float s = dloc[lr];
      unsigned w0 = fp8pk4(acc[0][rg] * s, acc[1][rg] * s, acc[2][rg] * s, acc[3][rg] * s);
      unsigned w1 = fp8pk4(acc[4][rg] * s, acc[5][rg] * s, acc[6][rg] * s, acc[7][rg] * s);
      Cb[(size_t)gr * 16 + m] = make_uint2(w0, w1);
    }
  }
}

// ---------------------------------------------------------------- fused agg1 + GEMM2 (+wp)
// Blocks >= gblocks compute wp from gapped r-runs — hidden under the gather.
__global__ __launch_bounds__(256) void k_aggemm(const uint4* __restrict__ hb,
                                                const float* __restrict__ dinv,
                                                const int* __restrict__ rowptr,
                                                const int* __restrict__ src,
                                                const float* __restrict__ biasH,
                                                const ushort* __restrict__ Wt,
                                                uint2* __restrict__ Cb,
                                                const unsigned* __restrict__ rpk,
                                                const int* __restrict__ rcur,
                                                float* __restrict__ wp,
                                                int N, int gblocks) {
  __shared__ __align__(16) ushort As[64 * 136];
  __shared__ __align__(16) ushort Bs[128 * 136];
  int t = threadIdx.x;

  if ((int)blockIdx.x >= gblocks) {  // ---- wp side-blocks
    float* wpl = (float*)As;  // 256 floats
    int b = blockIdx.x - gblocks;
    int node0 = b << 8;
    int nn = min(256, N - node0);
    int cnt = min(rcur[b * 16], SLOTS);
    wpl[t] = 0.f;
    __syncthreads();
    const unsigned* reg = rpk + (size_t)b * SLOTS;
    for (int j = t; j < cnt; j += 256) {
      unsigned w = reg[j];
      atomicAdd(&wpl[w >> 24], dinv[w & 0xFFFFFF]);
    }
    __syncthreads();
    if (t < nn) wp[node0 + t] = wpl[t];
    return;
  }

  int row0 = blockIdx.x * 64;
  {  // stage W2 while agg runs
    const uint4* W4 = (const uint4*)Wt;
    int rw = t >> 1, half = t & 1;
#pragma unroll
    for (int i = 0; i < 8; ++i) {
      uint4 v = W4[rw * 16 + half * 8 + i];
      *(uint4*)&Bs[rw * 136 + half * 64 + i * 8] = v;
    }
  }

  int tx = t & 7, ty = t >> 3;  // (8,32)
  float bv[16];
#pragma unroll
  for (int i = 0; i < 16; ++i) bv[i] = biasH[tx * 16 + i];

#pragma unroll
  for (int half = 0; half < 2; ++half) {
    int row = half * 32 + ty;
    int c = row0 + row;
    float o[16];
    if (c < N) {
      v2f acc[8] = {};
      gather_row(hb, rowptr, src, c, tx, acc);
      float s = dinv[c];
#pragma unroll
      for (int i = 0; i < 16; ++i) o[i] = fmaxf(acc[i >> 1][i & 1] * s + bv[i], 0.f);
    } else {
#pragma unroll
      for (int i = 0; i < 16; ++i) o[i] = 0.f;
    }
#pragma unroll
    for (int i = 0; i < 8; ++i)
      *(unsigned*)&As[row * 136 + tx * 16 + 2 * i] = bfpack2(o[2 * i], o[2 * i + 1]);
  }
  __syncthreads();

  int lane = t & 63, w = t >> 6;
  int m = lane & 15, quad = lane >> 4;
  f32x4 acc[8] = {};
#pragma unroll
  for (int kb = 0; kb < 128; kb += 32) {
    bf16x8 af = *(const bf16x8*)&As[(w * 16 + m) * 136 + kb + quad * 8];
#pragma unroll
    for (int nt = 0; nt < 8; ++nt) {
      bf16x8 bfv = *(const bf16x8*)&Bs[(nt * 16 + m) * 136 + kb + quad * 8];
      acc[nt] = __builtin_amdgcn_mfma_f32_16x16x32_bf16(af, bfv, acc[nt], 0, 0, 0);
    }
  }
#pragma unroll
  for (int reg = 0; reg < 4; ++reg) {
    int gr = row0 + w * 16 + quad * 4 + reg;
    if (gr < N) {
      float s = dinv[gr];
      unsigned w0 = fp8pk4(acc[0][reg] * s, acc[1][reg] * s, acc[2][reg] * s, acc[3][reg] * s);
      unsigned w1 = fp8pk4(acc[4][reg] * s, acc[5][reg] * s, acc[6][reg] * s, acc[7][reg] * s);
      Cb[(size_t)gr * 16 + m] = make_uint2(w0, w1);
    }
  }
}

// ---------------------------------------------------------------- FINAL aggregate
// (no fence/ticket — r4: per-block device fence collapsed gather rate 3x;
//  r10: even a fence-free returning-atomic ticket costs ~8us net)
__global__ __launch_bounds__(256) void k_aggfin(const uint4* __restrict__ hb,
                                                const float* __restrict__ dinv,
                                                const float* __restrict__ wp,
                                                const int* __restrict__ rowptr,
                                                const int* __restrict__ src,
                                                const float* __restrict__ biasH,
                                                float* __restrict__ part, int N) {
  int t = threadIdx.x;
  int tx = t & 7, ty = t >> 3;  // (8,32)
  float bv[16];
#pragma unroll
  for (int i = 0; i < 16; ++i) bv[i] = biasH[tx * 16 + i];
  float wacc[16];
#pragma unroll
  for (int i = 0; i < 16; ++i) wacc[i] = 0.f;

  for (int c = blockIdx.x * 32 + ty; c < N; c += gridDim.x * 32) {
    v2f acc[8] = {};
    gather_row(hb, rowptr, src, c, tx, acc);
    float s = dinv[c];
    float wt = (s + wp[c]) * s;
#pragma unroll
    for (int i = 0; i < 16; ++i)
      wacc[i] += wt * fmaxf(acc[i >> 1][i & 1] * s + bv[i], 0.f);
  }

  // wave reduce across ty (lane = ty*8+tx)
#pragma unroll
  for (int i = 0; i < 16; ++i) {
    wacc[i] += __shfl_down(wacc[i], 32);
    wacc[i] += __shfl_down(wacc[i], 16);
    wacc[i] += __shfl_down(wacc[i], 8);
  }
  __shared__ float redw[4][8][16];
  int wv = ty >> 3;
  if ((ty & 7) == 0) {
#pragma unroll
    for (int i = 0; i < 16; ++i) redw[wv][tx][i] = wacc[i];
  }
  __syncthreads();
  if (t < 128) {
    int cx = t >> 4, i = t & 15;
    float sum = redw[0][cx][i] + redw[1][cx][i] + redw[2][cx][i] + redw[3][cx][i];
    atomicAdd(&part[(size_t)(blockIdx.x & 63) * CH + cx * 16 + i], sum);
  }
}

// ---------------------------------------------------------------- epilogue (1024 thr)
__global__ __launch_bounds__(1024) void k_final(const float* __restrict__ partial,
                                                const float* __restrict__ W3,
                                                const float* __restrict__ b3,
                                                const float* __restrict__ Wl,
                                                const float* __restrict__ bl,
                                                float* __restrict__ out, float invN) {
  __shared__ float us[CH];
  __shared__ float red[8][CH];
  int t = threadIdx.x;
  int ch = t & 127, g = t >> 7;
  float s = 0.f;
#pragma unroll
  for (int b = 0; b < 8; ++b)
    s += partial[(size_t)(g * 8 + b) * CH + ch];
  red[g][ch] = s;
  __syncthreads();
  if (g == 0) {
    float u = 0.f;
#pragma unroll
    for (int k = 1; k < 8; ++k) u += red[k][ch];
    us[ch] = (s + u) * invN;
  }
  __syncthreads();
  float p = 0.f;
#pragma unroll
  for (int k = 0; k < 16; ++k) {
    int kk = g * 16 + k;
    int ko = (kk & 7) * 16 + (kk >> 3);  // un-permute channel
    p += us[kk] * W3[(size_t)ko * CH + ch];
  }
  red[g][ch] = p;
  __syncthreads();
  if (g == 0) {
    float S = red[0][ch];
#pragma unroll
    for (int k = 1; k < 8; ++k) S += red[k][ch];
    us[ch] = (S + b3[ch]) * Wl[ch];
  }
  __syncthreads();
  for (int off = 64; off > 0; off >>= 1) {
    if (t < off) us[t] += us[t + off];
    __syncthreads();
  }
  if (t == 0) out[0] = 1.f / (1.f + expf(-(us[0] + bl[0])));
}

// ---------------------------------------------------------------- launch

extern "C" void kernel_launch(void* const* d_in, const int* in_sizes, int n_in,
                              void* d_out, int out_size, void* d_ws, size_t ws_size,
                              hipStream_t stream) {
  const float* x  = (const float*)d_in[0];
  const void*  ei = d_in[1];
  const float* W1 = (const float*)d_in[3];
  const float* b1 = (const float*)d_in[4];
  const float* W2 = (const float*)d_in[5];
  const float* b2 = (const float*)d_in[6];
  const float* W3 = (const float*)d_in[7];
  const float* b3 = (const float*)d_in[8];
  const float* Wl = (const float*)d_in[9];
  const float* bl = (const float*)d_in[10];
  float* out = (float*)d_out;

  const int N = in_sizes[0] / CH;
  const int E = in_sizes[1] / 2;
  const int NB = (N + 255) >> 8;

  char* ws = (char*)d_ws;
  size_t off = 0;
  auto alloc = [&](size_t bytes) -> void* {
    void* p = ws + off;
    off += (bytes + 511) & ~(size_t)511;
    return p;
  };
  float*    dinv   = (float*)alloc((size_t)N * 4);
  int*      rowptr = (int*)alloc((size_t)(N + 1) * 4);
  ushort*   Wt1    = (ushort*)alloc(128 * 128 * 2);
  ushort*   Wt2    = (ushort*)alloc(128 * 128 * 2);
  float*    b1p    = (float*)alloc(CH * 4);
  float*    b2p    = (float*)alloc(CH * 4);
  float*    wp     = (float*)alloc((size_t)N * 4);
  int*      src    = (int*)alloc((size_t)E * 4);
  unsigned* cpk    = (unsigned*)alloc((size_t)256 * SLOTS * 4);  // gapped
  unsigned* rpk    = (unsigned*)alloc((size_t)256 * SLOTS * 4);  // gapped
  uint4*    hb     = (uint4*)alloc((size_t)N * 128);  // fp8 128B rows
  uint4*    xb     = (uint4*)alloc((size_t)N * 128);
  // ---- contiguous zero-init region (single small memset)
  size_t z0 = off;
  int*      gcur   = (int*)alloc(256 * 16 * 4);
  int*      rcur   = (int*)alloc(256 * 16 * 4);
  float*    part   = (float*)alloc((size_t)64 * CH * 4);
  size_t zbytes = off - z0;

  const int nCk = (E + CHUNK - 1) / CHUNK;
  const int gblocks = (N + 63) / 64;
  const int pgx = (N + 31) / 32;

  // ---- preprocessing (single-pass scatter; no counting pass)
  hipMemsetAsync(ws + z0, 0, zbytes, stream);
  kb_scat<<<nCk + 16, 256, 0, stream>>>(ei, gcur, rcur, cpk, rpk,
                                        W1, b1, W2, b2, Wt1, Wt2, b1p, b2p, E, N, nCk);
  // ---- CSR build + dinv + layer-1 GEMM (fused; register-prefetched inputs)
  kb_csrg1<<<NB, 1024, 0, stream>>>(cpk, gcur, rowptr, src, dinv, x, Wt1, (uint2*)hb, N);

  // ---- layer-1 aggregate + layer-2 GEMM, with wp side-blocks hidden under it
  k_aggemm<<<gblocks + NB, 256, 0, stream>>>(hb, dinv, rowptr, src, b1p, Wt2, (uint2*)xb,
                                             rpk, rcur, wp, N, gblocks);
  // ---- layer-2 aggregate fused with layer-3 collapse
  k_aggfin<<<pgx, 256, 0, stream>>>(xb, dinv, wp, rowptr, src, b2p, part, N);
  k_final<<<1, 1024, 0, stream>>>(part, W3, b3, Wl, bl, out, 1.0f / (float)N);
}